// Round 6
// baseline (382.657 us; speedup 1.0000x reference)
//
#include <hip/hip_runtime.h>

typedef unsigned short u16;
typedef unsigned int u32;
typedef unsigned long long u64;
typedef __bf16 bf16_t;
typedef bf16_t bf16x8 __attribute__((ext_vector_type(8)));
typedef float f32x4 __attribute__((ext_vector_type(4)));

typedef __attribute__((address_space(3))) u32 lds32_t;
typedef __attribute__((address_space(1))) u32 glb32_t;

#define DEV static __device__ __forceinline__
#define SBAR() asm volatile("s_barrier" ::: "memory")

DEV f32x4 mfma16(bf16x8 a, bf16x8 b, f32x4 c) {
  return __builtin_amdgcn_mfma_f32_16x16x32_bf16(a, b, c, 0, 0, 0);
}

DEV u16 f2bf(float f) { return __builtin_bit_cast(u16, (bf16_t)f); }
DEV u32 pk2(float a, float b) {
  return (u32)__builtin_bit_cast(u16, (bf16_t)a) |
         ((u32)__builtin_bit_cast(u16, (bf16_t)b) << 16);
}

// ===================== pack X: [4096][2048] bf16 = [zr | zi] =====================
__global__ __launch_bounds__(256) void pack_x(const float* __restrict__ zr,
                                              const float* __restrict__ zi,
                                              u16* __restrict__ X) {
  int idx = (blockIdx.x * 256 + threadIdx.x) * 4;
  int m = idx >> 11;
  int k = idx & 2047;
  const float* s = (k < 1024) ? (zr + m * 1024 + k) : (zi + m * 1024 + (k - 1024));
  f32x4 v = *(const f32x4*)s;
  u16* o = X + idx;
  o[0] = f2bf(v[0]); o[1] = f2bf(v[1]); o[2] = f2bf(v[2]); o[3] = f2bf(v[3]);
}

// ===================== pack weights into B^T layout [J][2048] bf16 =====================
template <int MODE>
__global__ __launch_bounds__(256) void pack_w(const float* __restrict__ w0r, const float* __restrict__ w0i,
                                              const float* __restrict__ w1r, const float* __restrict__ w1i,
                                              const float* __restrict__ w2r, const float* __restrict__ w2i,
                                              u16* __restrict__ out) {
  __shared__ u16 tile[64][68];
  int t = threadIdx.x;
  int j0 = blockIdx.x * 64;
  int k0 = blockIdx.y * 64;
  const float* src;
  float sign = 1.0f;
  int f0, r0;
  if (MODE == 0) {
    int section = j0 >> 11;
    int jj = j0 & 2047;
    int h = jj >> 7;
    bool real = ((jj & 127) < 64);
    f0 = h * 64;
    const float* wr = (section == 0) ? w0r : ((section == 1) ? w1r : w2r);
    const float* wi = (section == 0) ? w0i : ((section == 1) ? w1i : w2i);
    bool lowk = (k0 < 1024);
    r0 = lowk ? k0 : (k0 - 1024);
    if (real) { src = lowk ? wr : wi; sign = lowk ? 1.0f : -1.0f; }
    else      { src = lowk ? wi : wr; sign = 1.0f; }
  } else {
    int h = k0 >> 7;
    bool treal = ((k0 & 127) < 64);
    r0 = h * 64;
    bool lowj = (j0 < 1024);
    f0 = lowj ? j0 : (j0 - 1024);
    if (treal) { src = lowj ? w0r : w0i; sign = 1.0f; }
    else       { src = lowj ? w0i : w0r; sign = lowj ? -1.0f : 1.0f; }
  }
#pragma unroll
  for (int it = 0; it < 4; ++it) {
    int dk = it * 16 + (t >> 4);
    int df = (t & 15) * 4;
    f32x4 v = *(const f32x4*)(src + (size_t)(r0 + dk) * 1024 + f0 + df);
    u64 w = (u64)f2bf(sign * v[0]) | ((u64)f2bf(sign * v[1]) << 16) |
            ((u64)f2bf(sign * v[2]) << 32) | ((u64)f2bf(sign * v[3]) << 48);
    *(u64*)&tile[dk][df] = w;
  }
  __syncthreads();
#pragma unroll
  for (int it = 0; it < 4; ++it) {
    int df = it * 16 + (t >> 4);
    int dk0 = (t & 15) * 4;
    u64 w = (u64)tile[dk0][df] | ((u64)tile[dk0 + 1][df] << 16) |
            ((u64)tile[dk0 + 2][df] << 32) | ((u64)tile[dk0 + 3][df] << 48);
    *(u64*)(out + (size_t)(j0 + df) * 2048 + k0 + dk0) = w;
  }
}

// ===================== V transpose: C1 V-section -> VT[bh][d(128)][s(2048)] =====================
__global__ __launch_bounds__(256) void vtrans(const u16* __restrict__ C1, u16* __restrict__ VT) {
  __shared__ u16 tile[64][72];
  int t = threadIdx.x;
  int s0 = blockIdx.x * 64;
  int bh = blockIdx.y >> 1;
  int d0 = (blockIdx.y & 1) * 64;
  int b = bh >> 4, h = bh & 15;
  const u16* src = C1 + (size_t)(b * 2048 + s0) * 6144 + 4096 + h * 128 + d0;
#pragma unroll
  for (int it = 0; it < 2; ++it) {
    int ss = it * 32 + (t >> 3);
    int dd = (t & 7) * 8;
    uint4 v = *(const uint4*)(src + (size_t)ss * 6144 + dd);
    *(uint4*)&tile[ss][dd] = v;
  }
  __syncthreads();
#pragma unroll
  for (int it = 0; it < 2; ++it) {
    int dd = it * 32 + (t >> 3);
    int ss0 = (t & 7) * 8;
    union { u16 q[8]; uint4 v; } u;
#pragma unroll
    for (int i = 0; i < 8; ++i) u.q[i] = tile[ss0 + i][dd];
    *(uint4*)(VT + (size_t)(bh * 128 + d0 + dd) * 2048 + s0 + ss0) = u.v;
  }
}

// ===================== GEMM v2: counted-vmcnt phase engine =====================
// C[M][N] = A[M][2048] @ Bt[N][2048]^T.  Tile 128(M) x 256(N), BK=64, 8 waves.
// Per-wave 64x64 output, N interleaved: col = nh*128 + wc*32 + j*16 (nh = phase).
// LDS per buf: A[128][64] (16KB) + B[256][64] (32KB); 2 bufs = 96KB.
// Per K-tile: 2 phases x {ds_read (12/4 x b128, XOR-swizzled), stage half-tiles
// (A+B0 / B1 of tile T+1 -> other buf), counted vmcnt, barrier, 16 MFMA, barrier}.
// vmcnt derivation (per-wave, 6 load-instrs/K-tile): ph0 wait leaves <=4 (covers
// B1(T)), ph1 leaves <=2 (covers A,B0(T+1)). Never drains to 0 mid-loop (T4).
// Double barrier: pre-MFMA publishes all waves' vmcnt; post-MFMA prevents a fast
// wave's stage from overwriting LDS a slow wave still has ds_reads in flight on.
template <int W0, int W1, bool DOSTAGE>
DEV void kgroup(u16 (&lds)[2][24576], const u16* Asrc, const u16* Bsrc,
                f32x4 (&acc)[4][2][2], int cur, int ktn,
                int tid, int wr, int wc, int c, int g) {
  bf16x8 afr[4][2];
  bf16x8 bfr[2][2];
  // ---- phase 0 (nh = 0) ----
#pragma unroll
  for (int f = 0; f < 4; ++f)
#pragma unroll
    for (int kk = 0; kk < 2; ++kk) {
      int rowA = wr * 64 + f * 16 + c;
      int byte = rowA * 128 + ((kk * 64 + g * 16) ^ ((rowA & 7) << 4));
      afr[f][kk] = *(const bf16x8*)&lds[cur][byte >> 1];
    }
#pragma unroll
  for (int j = 0; j < 2; ++j)
#pragma unroll
    for (int kk = 0; kk < 2; ++kk) {
      int rowB = wc * 32 + j * 16 + c;
      int byte = rowB * 128 + ((kk * 64 + g * 16) ^ ((rowB & 7) << 4));
      bfr[j][kk] = *(const bf16x8*)&lds[cur][8192 + (byte >> 1)];
    }
  if (DOSTAGE) {
#pragma unroll
    for (int i = 0; i < 2; ++i) {  // A(ktn)
      int p = i * 8192 + tid * 16;
      int row = p >> 7;
      int inner = (p & 127) ^ ((row & 7) << 4);
      int col = (ktn * 128 + inner) >> 1;
      __builtin_amdgcn_global_load_lds((glb32_t*)(Asrc + (size_t)row * 2048 + col),
                                       (lds32_t*)&lds[cur ^ 1][p >> 1], 16, 0, 0);
    }
#pragma unroll
    for (int i = 0; i < 2; ++i) {  // B half 0 (ktn)
      int p = i * 8192 + tid * 16;
      int row = p >> 7;
      int inner = (p & 127) ^ ((row & 7) << 4);
      int col = (ktn * 128 + inner) >> 1;
      __builtin_amdgcn_global_load_lds((glb32_t*)(Bsrc + (size_t)row * 2048 + col),
                                       (lds32_t*)&lds[cur ^ 1][8192 + (p >> 1)], 16, 0, 0);
    }
  }
  asm volatile("s_waitcnt vmcnt(%0)" :: "i"(W0) : "memory");
  SBAR();
  __builtin_amdgcn_s_setprio(1);
#pragma unroll
  for (int f = 0; f < 4; ++f)
#pragma unroll
    for (int j = 0; j < 2; ++j)
#pragma unroll
      for (int kk = 0; kk < 2; ++kk)
        acc[f][0][j] = mfma16(afr[f][kk], bfr[j][kk], acc[f][0][j]);
  __builtin_amdgcn_s_setprio(0);
  SBAR();
  // ---- phase 1 (nh = 1) ----
#pragma unroll
  for (int j = 0; j < 2; ++j)
#pragma unroll
    for (int kk = 0; kk < 2; ++kk) {
      int rowB = 128 + wc * 32 + j * 16 + c;
      int byte = rowB * 128 + ((kk * 64 + g * 16) ^ ((rowB & 7) << 4));
      bfr[j][kk] = *(const bf16x8*)&lds[cur][8192 + (byte >> 1)];
    }
  if (DOSTAGE) {
#pragma unroll
    for (int i = 0; i < 2; ++i) {  // B half 1 (ktn)
      int p = i * 8192 + tid * 16;
      int row = 128 + (p >> 7);
      int inner = (p & 127) ^ ((row & 7) << 4);
      int col = (ktn * 128 + inner) >> 1;
      __builtin_amdgcn_global_load_lds((glb32_t*)(Bsrc + (size_t)row * 2048 + col),
                                       (lds32_t*)&lds[cur ^ 1][8192 + ((16384 + p) >> 1)], 16, 0, 0);
    }
  }
  asm volatile("s_waitcnt vmcnt(%0)" :: "i"(W1) : "memory");
  SBAR();
  __builtin_amdgcn_s_setprio(1);
#pragma unroll
  for (int f = 0; f < 4; ++f)
#pragma unroll
    for (int j = 0; j < 2; ++j)
#pragma unroll
      for (int kk = 0; kk < 2; ++kk)
        acc[f][1][j] = mfma16(afr[f][kk], bfr[j][kk], acc[f][1][j]);
  __builtin_amdgcn_s_setprio(0);
  SBAR();
}

template <int MODE>
__global__ __launch_bounds__(512, 2) void gemm2_bt(const u16* __restrict__ A,
                                                   const u16* __restrict__ Bt,
                                                   void* __restrict__ Cout) {
  __shared__ u16 lds[2][24576];
  int tid = threadIdx.x, lane = tid & 63, c = lane & 15, g = lane >> 4;
  int wid = tid >> 6, wr = wid >> 2, wc = wid & 3;
  size_t m0 = (size_t)blockIdx.y * 128, n0 = (size_t)blockIdx.x * 256;
  const u16* Asrc = A + m0 * 2048;
  const u16* Bsrc = Bt + n0 * 2048;

  f32x4 acc[4][2][2];
#pragma unroll
  for (int f = 0; f < 4; ++f)
#pragma unroll
    for (int nh = 0; nh < 2; ++nh)
#pragma unroll
      for (int j = 0; j < 2; ++j) acc[f][nh][j] = f32x4{0.f, 0.f, 0.f, 0.f};

  // prologue: stage tile 0 into buf 0 (A, B0, B1); wait A+B0 (leave B1 in flight)
#pragma unroll
  for (int i = 0; i < 2; ++i) {
    int p = i * 8192 + tid * 16;
    int row = p >> 7;
    int inner = (p & 127) ^ ((row & 7) << 4);
    int col = inner >> 1;
    __builtin_amdgcn_global_load_lds((glb32_t*)(Asrc + (size_t)row * 2048 + col),
                                     (lds32_t*)&lds[0][p >> 1], 16, 0, 0);
  }
#pragma unroll
  for (int i = 0; i < 2; ++i) {
    int p = i * 8192 + tid * 16;
    int row = p >> 7;
    int inner = (p & 127) ^ ((row & 7) << 4);
    int col = inner >> 1;
    __builtin_amdgcn_global_load_lds((glb32_t*)(Bsrc + (size_t)row * 2048 + col),
                                     (lds32_t*)&lds[0][8192 + (p >> 1)], 16, 0, 0);
  }
#pragma unroll
  for (int i = 0; i < 2; ++i) {
    int p = i * 8192 + tid * 16;
    int row = 128 + (p >> 7);
    int inner = (p & 127) ^ ((row & 7) << 4);
    int col = inner >> 1;
    __builtin_amdgcn_global_load_lds((glb32_t*)(Bsrc + (size_t)row * 2048 + col),
                                     (lds32_t*)&lds[0][8192 + ((16384 + p) >> 1)], 16, 0, 0);
  }
  asm volatile("s_waitcnt vmcnt(2)" ::: "memory");
  SBAR();

  int cur = 0;
  for (int T = 0; T < 31; ++T) {
    kgroup<4, 2, true>(lds, Asrc, Bsrc, acc, cur, T + 1, tid, wr, wc, c, g);
    cur ^= 1;
  }
  kgroup<0, 0, false>(lds, Asrc, Bsrc, acc, cur, 0, tid, wr, wc, c, g);

  if (MODE == 0) {
    u16* C = (u16*)Cout;
#pragma unroll
    for (int f = 0; f < 4; ++f)
#pragma unroll
      for (int nh = 0; nh < 2; ++nh)
#pragma unroll
        for (int j = 0; j < 2; ++j) {
          size_t row = m0 + wr * 64 + f * 16 + g * 4;
          size_t col = n0 + nh * 128 + wc * 32 + j * 16 + c;
#pragma unroll
          for (int r = 0; r < 4; ++r) C[(row + r) * 6144 + col] = f2bf(acc[f][nh][j][r]);
        }
  } else {
    float* Y = (float*)Cout;
#pragma unroll
    for (int f = 0; f < 4; ++f)
#pragma unroll
      for (int nh = 0; nh < 2; ++nh)
#pragma unroll
        for (int j = 0; j < 2; ++j) {
          size_t row = m0 + wr * 64 + f * 16 + g * 4;
          int col = (int)(n0 + nh * 128 + wc * 32 + j * 16 + c);
          float* base = (col < 1024) ? (Y + col) : (Y + 4194304 + (col - 1024));
#pragma unroll
          for (int r = 0; r < 4; ++r) base[(row + r) * 1024] = acc[f][nh][j][r];
        }
  }
}

// ===================== Flash attention v5 (unchanged from R5, proven) =====================
__global__ __launch_bounds__(512) void attn_fwd(const u16* __restrict__ C1,
                                                const u16* __restrict__ VT,
                                                u16* __restrict__ O) {
  __shared__ u16 Kl[2][8192];   // [64 kv][128 d], XOR-swizzled 16B slots per row
  __shared__ u16 Vl[2][9216];   // [128 d][72], kv 0..63 + pad 8

  int tid = threadIdx.x;
  int lane = tid & 63;
  int w = tid >> 6;
  int c = lane & 15, g = lane >> 4;
  int qt = blockIdx.x;
  int bh = blockIdx.y;
  int b = bh >> 4, h = bh & 15;
  const size_t LDC = 6144;
  const u16* Qb = C1 + (size_t)(b * 2048 + qt * 128 + w * 16) * LDC + h * 128;
  const u16* Ks = C1 + (size_t)(b * 2048) * LDC + 2048 + h * 128;
  const u16* Vs = VT + (size_t)bh * 128 * 2048;

  bf16x8 qf[4];
#pragma unroll
  for (int kk = 0; kk < 4; ++kk)
    qf[kk] = *(const bf16x8*)(Qb + (size_t)c * LDC + kk * 32 + g * 8);

  float mrunS = -3e38f, lrun = 0.f;
  f32x4 o[8];
#pragma unroll
  for (int nt = 0; nt < 8; ++nt) o[nt] = f32x4{0.f, 0.f, 0.f, 0.f};

  const float SC = 0.125f * 1.44269504f;  // SCALE * log2(e)
  const int kr = tid >> 4, ksl = tid & 15;
  const int vd = tid >> 2, vs = tid & 3;

#pragma unroll
  for (int i = 0; i < 2; ++i) {
    int row = i * 32 + kr;
    __builtin_amdgcn_global_load_lds(
        (glb32_t*)(Ks + (size_t)row * LDC + ((ksl ^ (kr & 15)) << 3)),
        (lds32_t*)&Kl[0][(i * 512 + tid) * 8], 16, 0, 0);
    uint4 vr = *(const uint4*)(Vs + (size_t)vd * 2048 + i * 32 + vs * 8);
    *(uint4*)&Vl[0][vd * 72 + i * 32 + vs * 8] = vr;
  }
  __syncthreads();

  int cur = 0;
  uint4 vreg[2];
  for (int t = 0; t < 32; ++t) {
    if (t < 31) {
      int kvn = (t + 1) * 64;
      vreg[0] = *(const uint4*)(Vs + (size_t)vd * 2048 + kvn + vs * 8);
      vreg[1] = *(const uint4*)(Vs + (size_t)vd * 2048 + kvn + 32 + vs * 8);
#pragma unroll
      for (int i = 0; i < 2; ++i) {
        int row = i * 32 + kr;
        __builtin_amdgcn_global_load_lds(
            (glb32_t*)(Ks + (size_t)(kvn + row) * LDC + ((ksl ^ (kr & 15)) << 3)),
            (lds32_t*)&Kl[cur ^ 1][(i * 512 + tid) * 8], 16, 0, 0);
      }
    }

    f32x4 s[4];
#pragma unroll
    for (int m = 0; m < 4; ++m) s[m] = f32x4{0.f, 0.f, 0.f, 0.f};
#pragma unroll
    for (int m = 0; m < 4; ++m)
#pragma unroll
      for (int kk = 0; kk < 4; ++kk) {
        bf16x8 kf = *(const bf16x8*)&Kl[cur][(16 * m + c) * 128 + (((4 * kk + g) ^ c) << 3)];
        s[m] = mfma16(kf, qf[kk], s[m]);
      }

    float mx01 = fmaxf(fmaxf(s[0][0], s[0][1]), fmaxf(s[0][2], s[0][3]));
    float mx23 = fmaxf(fmaxf(s[1][0], s[1][1]), fmaxf(s[1][2], s[1][3]));
    float mx45 = fmaxf(fmaxf(s[2][0], s[2][1]), fmaxf(s[2][2], s[2][3]));
    float mx67 = fmaxf(fmaxf(s[3][0], s[3][1]), fmaxf(s[3][2], s[3][3]));
    float mx = fmaxf(fmaxf(mx01, mx23), fmaxf(mx45, mx67));
    if (!__all(mx * SC <= mrunS + 8.0f)) {
      mx = fmaxf(mx, __shfl_xor(mx, 16));
      mx = fmaxf(mx, __shfl_xor(mx, 32));
      float mn = fmaxf(mrunS, mx * SC);
      float al = exp2f(mrunS - mn);
      mrunS = mn;
      float alr[4];
#pragma unroll
      for (int r = 0; r < 4; ++r) alr[r] = __shfl(al, 4 * g + r);
#pragma unroll
      for (int nt = 0; nt < 8; ++nt)
#pragma unroll
        for (int r = 0; r < 4; ++r) o[nt][r] *= alr[r];
      lrun *= al;
    }
    float p[16];
#pragma unroll
    for (int m = 0; m < 4; ++m)
#pragma unroll
      for (int r = 0; r < 4; ++r) p[4 * m + r] = exp2f(fmaf(s[m][r], SC, -mrunS));
    float sA = (p[0] + p[1]) + (p[2] + p[3]);
    float sB = (p[4] + p[5]) + (p[6] + p[7]);
    float sC2 = (p[8] + p[9]) + (p[10] + p[11]);
    float sD = (p[12] + p[13]) + (p[14] + p[15]);
    lrun += (sA + sB) + (sC2 + sD);

    u32 d[8];
#pragma unroll
    for (int m = 0; m < 4; ++m) {
      d[2 * m] = pk2(p[4 * m], p[4 * m + 1]);
      d[2 * m + 1] = pk2(p[4 * m + 2], p[4 * m + 3]);
    }

    union { u32 dw[4]; bf16x8 v; } pa0, pa1;
#pragma unroll
    for (int b2 = 0; b2 < 2; ++b2) {
      u32 x0 = d[b2], x1 = d[2 + b2];
      asm("v_permlane32_swap_b32 %0, %1" : "+v"(x0), "+v"(x1));
      asm("v_permlane16_swap_b32 %0, %1" : "+v"(x0), "+v"(x1));
      pa0.dw[b2] = x0; pa0.dw[2 + b2] = x1;
      u32 y0 = d[4 + b2], y1 = d[6 + b2];
      asm("v_permlane32_swap_b32 %0, %1" : "+v"(y0), "+v"(y1));
      asm("v_permlane16_swap_b32 %0, %1" : "+v"(y0), "+v"(y1));
      pa1.dw[b2] = y0; pa1.dw[2 + b2] = y1;
    }

#pragma unroll
    for (int nt = 0; nt < 8; ++nt) {
      bf16x8 vf0 = *(const bf16x8*)&Vl[cur][(nt * 16 + c) * 72 + g * 8];
      bf16x8 vf1 = *(const bf16x8*)&Vl[cur][(nt * 16 + c) * 72 + 32 + g * 8];
      o[nt] = mfma16(pa0.v, vf0, o[nt]);
      o[nt] = mfma16(pa1.v, vf1, o[nt]);
    }

    if (t < 31) {
      *(uint4*)&Vl[cur ^ 1][vd * 72 + vs * 8] = vreg[0];
      *(uint4*)&Vl[cur ^ 1][vd * 72 + 32 + vs * 8] = vreg[1];
    }
    __syncthreads();
    cur ^= 1;
  }

  lrun += __shfl_xor(lrun, 16);
  lrun += __shfl_xor(lrun, 32);
  float inv = 1.0f / lrun;
  float invr[4];
#pragma unroll
  for (int r = 0; r < 4; ++r) invr[r] = __shfl(inv, 4 * g + r);
#pragma unroll
  for (int nt = 0; nt < 8; ++nt)
#pragma unroll
    for (int r = 0; r < 4; ++r) {
      size_t row = (size_t)(b * 2048 + qt * 128 + w * 16 + 4 * g + r);
      O[row * 2048 + h * 128 + nt * 16 + c] = f2bf(o[nt][r] * invr[r]);
    }
}

// ===================== launch =====================
extern "C" void kernel_launch(void* const* d_in, const int* in_sizes, int n_in,
                              void* d_out, int out_size, void* d_ws, size_t ws_size,
                              hipStream_t stream) {
  const float* zr   = (const float*)d_in[0];
  const float* zi   = (const float*)d_in[1];
  const float* wq_r = (const float*)d_in[2];
  const float* wq_i = (const float*)d_in[3];
  const float* wk_r = (const float*)d_in[4];
  const float* wk_i = (const float*)d_in[5];
  const float* wv_r = (const float*)d_in[6];
  const float* wv_i = (const float*)d_in[7];
  const float* wo_r = (const float*)d_in[8];
  const float* wo_i = (const float*)d_in[9];

  if (ws_size < (size_t)134217728) return;  // need 128 MiB scratch

  char* ws = (char*)d_ws;
  u16* X    = (u16*)(ws + 0);          //  16 MiB: [4096][2048]
  u16* Wqkv = (u16*)(ws + 16777216);   //  24 MiB: [6144][2048]
  u16* C1   = (u16*)(ws + 41943040);   //  48 MiB: [4096][6144] = [Q|K|V] head-interleaved
  u16* VT   = (u16*)(ws + 92274688);   //  16 MiB: [32][128][2048]
  u16* O    = (u16*)(ws + 109051904);  //  16 MiB: [4096][2048]
  u16* Wo   = (u16*)(ws + 125829120);  //   8 MiB: [2048][2048]

  pack_x<<<8192, 256, 0, stream>>>(zr, zi, X);
  pack_w<0><<<dim3(96, 32), 256, 0, stream>>>(wq_r, wq_i, wk_r, wk_i, wv_r, wv_i, Wqkv);
  pack_w<1><<<dim3(32, 32), 256, 0, stream>>>(wo_r, wo_i, wo_r, wo_i, wo_r, wo_i, Wo);
  gemm2_bt<0><<<dim3(24, 32), 512, 0, stream>>>(X, Wqkv, C1);
  vtrans<<<dim3(32, 64), 256, 0, stream>>>(C1, VT);
  attn_fwd<<<dim3(16, 32), 512, 0, stream>>>(C1, VT, O);
  gemm2_bt<1><<<dim3(8, 32), 512, 0, stream>>>(O, Wo, (float*)d_out);
}